// Round 7
// baseline (76.508 us; speedup 1.0000x reference)
//
#include <hip/hip_runtime.h>
#include <math.h>

#define BSZ 16
#define NP 4096
#define MAXGT 32
#define CIN 512
#define NCLS 4
#define RPB 128                    // rows per block
#define NBLK (BSZ * NP / RPB)      // 512 blocks
#define BPB (NP / RPB)             // 32 blocks per batch

typedef float f32x4 __attribute__((ext_vector_type(4)));

// async global->LDS, 16B per lane; dest = uniform base + lane*16 (HW rule)
__device__ __forceinline__ void dma16(const void* g, void* l) {
    __builtin_amdgcn_global_load_lds(
        (const __attribute__((address_space(1))) void*)g,
        (__attribute__((address_space(3))) void*)l, 16, 0, 0);
}

// ---------------------------------------------------------------------------
// Main kernel: 512 blocks x 256 thr (4 waves), 128 rows/block. v is staged
// into LDS in 8 double-buffered 32KB phases (64 rows x 128-float K-quarter)
// via global_load_lds; the LDS dest stays linear and the XOR bank-swizzle
// (byte ^= ((row&7)<<4)) is pre-applied to the per-lane GLOBAL source, with
// the same XOR on the ds_read side -> conflict-free b128 reads. Compute:
// wave kw handles k-sub [kq*128+kw*32, +32) for all 64 rows of the phase's
// half (k wave-uniform -> s_load weights). Epilogue (identical math to R3)
// runs on 2 waves after a cross-wave LDS reduce in the reused arena.
// ---------------------------------------------------------------------------
__global__ __launch_bounds__(256, 2) void oicr_main(
    const float* __restrict__ v,
    const float* __restrict__ gt_boxes,
    const int*   __restrict__ gt_counts,
    const float* __restrict__ rois,
    const float* __restrict__ labels,
    const float* __restrict__ pre_score,
    const float* __restrict__ cls_w,
    const float* __restrict__ cls_b,
    const float* __restrict__ reg_w,
    const float* __restrict__ reg_b,
    float* __restrict__ partials)
{
    __shared__ __align__(16) char arena[2][32768];   // 64 KB phase buffers
    __shared__ float s_bias[8];
    __shared__ float g_x0[MAXGT], g_y0[MAXGT], g_x1[MAXGT], g_y1[MAXGT];
    __shared__ float g_area[MAXGT];
    __shared__ int   g_valid[MAXGT];
    __shared__ int   s_label;
    __shared__ float red2[2][4];

    const int tid  = threadIdx.x;
    const int lane = tid & 63;
    const int wv   = tid >> 6;
    const int kw   = __builtin_amdgcn_readfirstlane(wv);  // wave-uniform wave id
    const int blk  = blockIdx.x;
    const int b    = blk >> 5;                 // 32 blocks per batch
    const int row0 = blk * RPB;                // block's first global row

    // --- tiny per-batch metadata ---
    if (tid < 8) s_bias[tid] = (tid < 4) ? cls_b[tid] : reg_b[tid - 4];
    if (tid < MAXGT) {
        int cnt = gt_counts[b];
        const float* g = gt_boxes + (size_t)(b * MAXGT + tid) * 4;
        float x0 = g[0], y0 = g[1], x1 = g[2], y1 = g[3];
        g_x0[tid] = x0; g_y0[tid] = y0; g_x1[tid] = x1; g_y1[tid] = y1;
        g_area[tid] = (x1 - x0) * (y1 - y0);
        g_valid[tid] = (tid < cnt) ? 1 : 0;
    }
    if (tid == 0) {
        const float* L = labels + b * NCLS;
        int bi = 0; float bv = L[0];
        #pragma unroll
        for (int c = 1; c < NCLS; ++c) { if (L[c] > bv) { bv = L[c]; bi = c; } }
        s_label = bi;
    }

    // phase P: half h=P&1 (rows h*64..h*64+63), K-quarter kq=P>>1.
    // 32KB = 32 DMA instrs (4 waves x 8). Source byte pre-swizzled so that
    // lds[D] = chunk[D ^ ((rowOf(D)&7)<<4)], rowOf(D)=D>>9.
    #define STAGE(P, BB) do {                                                  \
        const int h_ = (P) & 1, kq_ = (P) >> 1;                                \
        const char* gb_ = (const char*)v +                                     \
            ((size_t)(row0 + h_ * 64) * CIN + (size_t)kq_ * 128) * 4;          \
        char* lb_ = &arena[BB][0] + kw * 8192;                                 \
        _Pragma("unroll")                                                      \
        for (int pp_ = 0; pp_ < 8; ++pp_) {                                    \
            const int D_ = kw * 8192 + pp_ * 1024 + lane * 16;                 \
            const int F_ = D_ ^ (((D_ >> 9) & 7) << 4);                        \
            const int rf_ = F_ >> 9, ko_ = F_ & 511;                           \
            dma16(gb_ + (size_t)rf_ * (CIN * 4) + ko_, lb_ + pp_ * 1024);      \
        }                                                                      \
    } while (0)

    float accA[8], accB[8];
    #pragma unroll
    for (int c = 0; c < 8; ++c) { accA[c] = 0.f; accB[c] = 0.f; }

    STAGE(0, 0);
    __syncthreads();

    #pragma unroll
    for (int p = 0; p < 8; ++p) {
        if (p < 7) STAGE(p + 1, (p + 1) & 1);
        const int kq = p >> 1;
        const char* bp = &arena[p & 1][0];
        #pragma unroll
        for (int j = 0; j < 8; ++j) {
            const int A  = lane * 512 + kw * 128 + j * 16;
            const int As = A ^ ((lane & 7) << 4);
            f32x4 a = *(const f32x4*)(bp + As);
            const int k = kq * 128 + kw * 32 + j * 4;     // wave-uniform
            #pragma unroll
            for (int c = 0; c < 4; ++c) {
                const f32x4 wc = *(const f32x4*)&cls_w[c * CIN + k]; // s_load
                const f32x4 wr = *(const f32x4*)&reg_w[c * CIN + k]; // s_load
                if ((p & 1) == 0) {
                    accA[c]     += a[0]*wc[0] + a[1]*wc[1] + a[2]*wc[2] + a[3]*wc[3];
                    accA[4 + c] += a[0]*wr[0] + a[1]*wr[1] + a[2]*wr[2] + a[3]*wr[3];
                } else {
                    accB[c]     += a[0]*wc[0] + a[1]*wc[1] + a[2]*wc[2] + a[3]*wc[3];
                    accB[4 + c] += a[0]*wr[0] + a[1]*wr[1] + a[2]*wr[2] + a[3]*wr[3];
                }
            }
        }
        __syncthreads();
    }
    #undef STAGE

    // --- cross-wave reduce via arena[0] (free now): red8[4][128][8] ---
    float* red8 = (float*)&arena[0][0];
    #pragma unroll
    for (int c = 0; c < 8; ++c) {
        red8[((kw * 128) + lane) * 8 + c]      = accA[c];
        red8[((kw * 128) + 64 + lane) * 8 + c] = accB[c];
    }
    __syncthreads();

    // --- epilogue on 2 waves: thread t < 128 handles block-row t ---
    float px = 0.f, py = 0.f, pz = 0.f, pw = 0.f;
    if (tid < 128) {
        const int row = row0 + tid;
        float acc[8];
        #pragma unroll
        for (int c = 0; c < 8; ++c)
            acc[c] = red8[(0 * 128 + tid) * 8 + c] + red8[(1 * 128 + tid) * 8 + c]
                   + red8[(2 * 128 + tid) * 8 + c] + red8[(3 * 128 + tid) * 8 + c];

        const float cls0 = acc[0] + s_bias[0];
        const float cls1 = acc[1] + s_bias[1];
        const float cls2 = acc[2] + s_bias[2];
        const float cls3 = acc[3] + s_bias[3];
        const float reg0 = acc[4] + s_bias[4];
        const float reg1 = acc[5] + s_bias[5];
        const float reg2 = acc[6] + s_bias[6];
        const float reg3 = acc[7] + s_bias[7];

        const int lbl = s_label;

        float mB = fmaxf(fmaxf(cls0, cls1), fmaxf(cls2, cls3));
        float lseB = mB + logf(expf(cls0 - mB) + expf(cls1 - mB) +
                               expf(cls2 - mB) + expf(cls3 - mB));
        float clsL = (lbl == 0) ? cls0 : (lbl == 1) ? cls1 : (lbl == 2) ? cls2 : cls3;
        float ce_bg = lseB - clsL;

        const float lo = 1e-7f, hi2 = 1.f - 1e-7f;
        float cc0 = fminf(fmaxf(cls0, lo), hi2);
        float cc1 = fminf(fmaxf(cls1, lo), hi2);
        float cc2 = fminf(fmaxf(cls2, lo), hi2);
        float cc3 = fminf(fmaxf(cls3, lo), hi2);
        float mF = fmaxf(fmaxf(cc0, cc1), fmaxf(cc2, cc3));
        float lseF = mF + logf(expf(cc0 - mF) + expf(cc1 - mF) +
                               expf(cc2 - mF) + expf(cc3 - mF));
        float ccL = (lbl == 0) ? cc0 : (lbl == 1) ? cc1 : (lbl == 2) ? cc2 : cc3;
        float ce_fg = lseF - ccL;
        float ps = pre_score[(size_t)row * NCLS + lbl];

        float4 r = *(const float4*)(rois + (size_t)row * 4);
        float rarea = (r.z - r.x) * (r.w - r.y);
        float best = -3.0e38f;
        int   bi = 0;
        int   mk = 0;
        #pragma unroll
        for (int g = 0; g < MAXGT; ++g) {
            float ix0 = fmaxf(r.x, g_x0[g]);
            float iy0 = fmaxf(r.y, g_y0[g]);
            float ix1 = fminf(r.z, g_x1[g]);
            float iy1 = fminf(r.w, g_y1[g]);
            float iw = fmaxf(ix1 - ix0, 0.f);
            float ih = fmaxf(iy1 - iy0, 0.f);
            float inter = iw * ih;
            float iou = inter / (g_area[g] + rarea - inter);
            iou = g_valid[g] ? iou : -1.0f;
            if (iou > best) { best = iou; bi = g; }   // strict > => first max
            mk |= (iou > 0.5f) ? 1 : 0;
        }
        float maskf = mk ? 1.f : 0.f;

        float gx0 = g_x0[bi], gy0 = g_y0[bi], gx1 = g_x1[bi], gy1 = g_y1[bi];
        float gx = (gx1 + gx0) * 0.5f, gy = (gy1 + gy0) * 0.5f;
        float gw = (gx1 - gx0) * 0.5f, gh = (gy1 - gy0) * 0.5f;
        float rx = (r.z + r.x) * 0.5f, ry = (r.w + r.y) * 0.5f;
        float rw = (r.z - r.x) * 0.5f, rh = (r.w - r.y) * 0.5f;
        float tx = (gx - rx) / (rw + 1e-8f);
        float ty = (gy - ry) / (rh + 1e-8f);
        float tw = logf(gw / (rw + 1e-8f));
        float th = logf(gh / (rh + 1e-8f));

        float d0 = reg0 - tx, d1 = reg1 - ty, d2 = reg2 - tw, d3 = reg3 - th;
        float a0 = fabsf(d0), a1 = fabsf(d1), a2 = fabsf(d2), a3 = fabsf(d3);
        float s0 = (a0 < 1.f) ? 0.5f * a0 * a0 : a0 - 0.5f;
        float s1 = (a1 < 1.f) ? 0.5f * a1 * a1 : a1 - 0.5f;
        float s2 = (a2 < 1.f) ? 0.5f * a2 * a2 : a2 - 0.5f;
        float s3 = (a3 < 1.f) ? 0.5f * a3 * a3 : a3 - 0.5f;
        float sl1 = s0 + s1 + s2 + s3;

        px = ce_bg;
        py = ce_fg * ps * maskf;
        pz = maskf;
        pw = sl1 * maskf * ps;

        #pragma unroll
        for (int off = 32; off > 0; off >>= 1) {
            px += __shfl_down(px, off);
            py += __shfl_down(py, off);
            pz += __shfl_down(pz, off);
            pw += __shfl_down(pw, off);
        }
        if (lane == 0) {
            red2[wv][0] = px; red2[wv][1] = py;
            red2[wv][2] = pz; red2[wv][3] = pw;
        }
    }
    __syncthreads();
    if (tid == 0) {
        partials[(size_t)blk * 4 + 0] = red2[0][0] + red2[1][0];
        partials[(size_t)blk * 4 + 1] = red2[0][1] + red2[1][1];
        partials[(size_t)blk * 4 + 2] = red2[0][2] + red2[1][2];
        partials[(size_t)blk * 4 + 3] = red2[0][3] + red2[1][3];
    }
}

// ---------------------------------------------------------------------------
// Final combine: lanes 0..15 each sum their batch's 32 block-partials in
// fixed order, compute per-batch terms, wave shuffle-reduce, one write.
// ---------------------------------------------------------------------------
__global__ __launch_bounds__(64) void oicr_final(
    const float* __restrict__ partials,
    const int*   __restrict__ gt_counts,
    float* __restrict__ out)
{
    const int lane = threadIdx.x;
    float S0 = 0.f, S1 = 0.f, S2 = 0.f, S3 = 0.f;
    float c_term = 0.f, cbg_term = 0.f, bg_term = 0.f, l1_term = 0.f;
    if (lane < BSZ) {
        for (int blk = 0; blk < BPB; ++blk) {
            const float* q = partials + (size_t)(lane * BPB + blk) * 4;
            S0 += q[0]; S1 += q[1]; S2 += q[2]; S3 += q[3];
        }
        bool has = gt_counts[lane] > 0;
        float c_fg       = S1 / (S2 + 1e-7f);
        float ce_bg_mean = S0 / (float)NP;
        float l1b        = S3 / (float)(BSZ * NP);
        c_term   = has ? c_fg : 0.f;
        cbg_term = has ? 0.f : ce_bg_mean;
        bg_term  = has ? 0.f : (float)NP;
        l1_term  = has ? l1b : 0.f;
    }
    #pragma unroll
    for (int off = 32; off > 0; off >>= 1) {
        c_term   += __shfl_down(c_term, off);
        cbg_term += __shfl_down(cbg_term, off);
        bg_term  += __shfl_down(bg_term, off);
        l1_term  += __shfl_down(l1_term, off);
    }
    if (lane == 0) {
        out[0] = (c_term + cbg_term / (bg_term + 1e-7f)) / ((float)BSZ + 1e-7f)
                 + l1_term;
    }
}

extern "C" void kernel_launch(void* const* d_in, const int* in_sizes, int n_in,
                              void* d_out, int out_size, void* d_ws, size_t ws_size,
                              hipStream_t stream)
{
    const float* v         = (const float*)d_in[0];
    const float* gt_boxes  = (const float*)d_in[1];
    const int*   gt_counts = (const int*)  d_in[2];
    const float* rois      = (const float*)d_in[3];
    const float* labels    = (const float*)d_in[4];
    const float* pre_score = (const float*)d_in[5];
    const float* cls_w     = (const float*)d_in[6];
    const float* cls_b     = (const float*)d_in[7];
    const float* reg_w     = (const float*)d_in[8];
    const float* reg_b     = (const float*)d_in[9];
    float* out      = (float*)d_out;
    float* partials = (float*)d_ws;   // 512 blocks * 4 floats = 8 KB

    oicr_main<<<dim3(NBLK), dim3(256), 0, stream>>>(
        v, gt_boxes, gt_counts, rois, labels, pre_score,
        cls_w, cls_b, reg_w, reg_b, partials);
    oicr_final<<<dim3(1), dim3(64), 0, stream>>>(partials, gt_counts, out);
}

// Round 8
// 54.537 us; speedup vs baseline: 1.4029x; 1.4029x over previous
//
#include <hip/hip_runtime.h>
#include <math.h>

#define BSZ 16
#define NP 4096
#define MAXGT 32
#define CIN 512
#define NCLS 4
#define RPT 2                      // rows (proposals) per thread
#define PB (64 * RPT)              // proposals per block = 128
#define NBLK (BSZ * NP / PB)       // 512 blocks
#define BPB (NP / PB)              // 32 blocks per batch

typedef float f32x4 __attribute__((ext_vector_type(4)));

// ---------------------------------------------------------------------------
// Main kernel (R3 champion + deeper pipeline probe): 4 waves/block, 128
// proposals/block (2/thread). Wave w computes dot-product partials over
// K-quarter w; weights read via wave-uniform addresses (scalar K$ path, no
// LDS). v streamed with plain cached loads (1 miss + 7 L1 hits per 128B
// line per lane). unroll 16 + uncapped VGPRs: up to 32 loads in flight per
// thread to test whether the wall is latency absorption or MSHR capacity.
// ---------------------------------------------------------------------------
__global__ __launch_bounds__(256) void oicr_main(
    const float* __restrict__ v,
    const float* __restrict__ gt_boxes,
    const int*   __restrict__ gt_counts,
    const float* __restrict__ rois,
    const float* __restrict__ labels,
    const float* __restrict__ pre_score,
    const float* __restrict__ cls_w,
    const float* __restrict__ cls_b,
    const float* __restrict__ reg_w,
    const float* __restrict__ reg_b,
    float* __restrict__ partials)
{
    __shared__ float red8[4][PB][9];      // 18.4 KB, stride 9 -> conflict-free
    __shared__ float s_bias[8];
    __shared__ float g_x0[MAXGT], g_y0[MAXGT], g_x1[MAXGT], g_y1[MAXGT];
    __shared__ float g_area[MAXGT];
    __shared__ int   g_valid[MAXGT];
    __shared__ int   s_label;

    const int tid   = threadIdx.x;
    const int lane  = tid & 63;
    const int wv    = tid >> 6;                   // wave id 0..3 (K-quarter)
    const int blk   = blockIdx.x;
    const int b     = blk >> 5;                   // 32 blocks per batch
    const int pbase = (blk & 31) * PB;
    const int row0  = b * NP + pbase + lane;      // this thread's 2 rows
    const int row1  = row0 + 64;

    // --- tiny per-batch metadata (consumed only after the barrier) ---
    if (tid < 8) s_bias[tid] = (tid < 4) ? cls_b[tid] : reg_b[tid - 4];
    if (tid < MAXGT) {
        int cnt = gt_counts[b];
        const float* g = gt_boxes + (size_t)(b * MAXGT + tid) * 4;
        float x0 = g[0], y0 = g[1], x1 = g[2], y1 = g[3];
        g_x0[tid] = x0; g_y0[tid] = y0; g_x1[tid] = x1; g_y1[tid] = y1;
        g_area[tid] = (x1 - x0) * (y1 - y0);
        g_valid[tid] = (tid < cnt) ? 1 : 0;
    }
    if (tid == 0) {
        const float* L = labels + b * NCLS;
        int bi = 0; float bv = L[0];
        #pragma unroll
        for (int c = 1; c < NCLS; ++c) { if (L[c] > bv) { bv = L[c]; bi = c; } }
        s_label = bi;
    }

    // --- dot-product partials over this wave's K-quarter, 2 rows/thread ---
    const int kq = __builtin_amdgcn_readfirstlane(wv);   // wave-uniform
    float acc0[8], acc1[8];
    #pragma unroll
    for (int c = 0; c < 8; ++c) { acc0[c] = 0.f; acc1[c] = 0.f; }

    const f32x4* vr0 = (const f32x4*)(v + (size_t)row0 * CIN) + kq * 32;
    const f32x4* vr1 = (const f32x4*)(v + (size_t)row1 * CIN) + kq * 32;

    #pragma unroll 16
    for (int i = 0; i < 32; ++i) {
        f32x4 a0 = vr0[i];
        f32x4 a1 = vr1[i];
        const int k = (kq * 32 + i) * 4;             // uniform
        #pragma unroll
        for (int c = 0; c < 4; ++c) {
            const f32x4 wc = *(const f32x4*)&cls_w[c * CIN + k];  // uniform -> s_load
            const f32x4 wr = *(const f32x4*)&reg_w[c * CIN + k];  // uniform -> s_load
            acc0[c]     += a0[0]*wc[0] + a0[1]*wc[1] + a0[2]*wc[2] + a0[3]*wc[3];
            acc1[c]     += a1[0]*wc[0] + a1[1]*wc[1] + a1[2]*wc[2] + a1[3]*wc[3];
            acc0[4 + c] += a0[0]*wr[0] + a0[1]*wr[1] + a0[2]*wr[2] + a0[3]*wr[3];
            acc1[4 + c] += a1[0]*wr[0] + a1[1]*wr[1] + a1[2]*wr[2] + a1[3]*wr[3];
        }
    }

    #pragma unroll
    for (int c = 0; c < 8; ++c) {
        red8[wv][lane][c]      = acc0[c];
        red8[wv][64 + lane][c] = acc1[c];
    }
    __syncthreads();

    if (wv != 0) return;   // no barriers below

    // --- wave 0: combine K-quarters + epilogue for both rows ---
    float px = 0.f, py = 0.f, pz = 0.f, pw = 0.f;

    #pragma unroll
    for (int rr = 0; rr < RPT; ++rr) {
        const int li  = rr * 64 + lane;
        const int row = row0 + rr * 64;

        float acc[8];
        #pragma unroll
        for (int c = 0; c < 8; ++c)
            acc[c] = red8[0][li][c] + red8[1][li][c] +
                     red8[2][li][c] + red8[3][li][c];

        const float cls0 = acc[0] + s_bias[0];
        const float cls1 = acc[1] + s_bias[1];
        const float cls2 = acc[2] + s_bias[2];
        const float cls3 = acc[3] + s_bias[3];
        const float reg0 = acc[4] + s_bias[4];
        const float reg1 = acc[5] + s_bias[5];
        const float reg2 = acc[6] + s_bias[6];
        const float reg3 = acc[7] + s_bias[7];

        const int lbl = s_label;

        // background CE on raw logits
        float mB = fmaxf(fmaxf(cls0, cls1), fmaxf(cls2, cls3));
        float lseB = mB + logf(expf(cls0 - mB) + expf(cls1 - mB) +
                               expf(cls2 - mB) + expf(cls3 - mB));
        float clsL = (lbl == 0) ? cls0 : (lbl == 1) ? cls1 : (lbl == 2) ? cls2 : cls3;
        float ce_bg = lseB - clsL;

        // foreground CE on clipped logits
        const float lo = 1e-7f, hi2 = 1.f - 1e-7f;
        float cc0 = fminf(fmaxf(cls0, lo), hi2);
        float cc1 = fminf(fmaxf(cls1, lo), hi2);
        float cc2 = fminf(fmaxf(cls2, lo), hi2);
        float cc3 = fminf(fmaxf(cls3, lo), hi2);
        float mF = fmaxf(fmaxf(cc0, cc1), fmaxf(cc2, cc3));
        float lseF = mF + logf(expf(cc0 - mF) + expf(cc1 - mF) +
                               expf(cc2 - mF) + expf(cc3 - mF));
        float ccL = (lbl == 0) ? cc0 : (lbl == 1) ? cc1 : (lbl == 2) ? cc2 : cc3;
        float ce_fg = lseF - ccL;
        float ps = pre_score[(size_t)row * NCLS + lbl];

        // IoU over 32 GTs: mask + first-occurrence argmax
        float4 r = *(const float4*)(rois + (size_t)row * 4);
        float rarea = (r.z - r.x) * (r.w - r.y);
        float best = -3.0e38f;
        int   bi = 0;
        int   mk = 0;
        #pragma unroll
        for (int g = 0; g < MAXGT; ++g) {
            float ix0 = fmaxf(r.x, g_x0[g]);
            float iy0 = fmaxf(r.y, g_y0[g]);
            float ix1 = fminf(r.z, g_x1[g]);
            float iy1 = fminf(r.w, g_y1[g]);
            float iw = fmaxf(ix1 - ix0, 0.f);
            float ih = fmaxf(iy1 - iy0, 0.f);
            float inter = iw * ih;
            float iou = inter / (g_area[g] + rarea - inter);
            iou = g_valid[g] ? iou : -1.0f;
            if (iou > best) { best = iou; bi = g; }   // strict > => first max
            mk |= (iou > 0.5f) ? 1 : 0;
        }
        float maskf = mk ? 1.f : 0.f;

        // bbox targets + smooth L1
        float gx0 = g_x0[bi], gy0 = g_y0[bi], gx1 = g_x1[bi], gy1 = g_y1[bi];
        float gx = (gx1 + gx0) * 0.5f, gy = (gy1 + gy0) * 0.5f;
        float gw = (gx1 - gx0) * 0.5f, gh = (gy1 - gy0) * 0.5f;
        float rx = (r.z + r.x) * 0.5f, ry = (r.w + r.y) * 0.5f;
        float rw = (r.z - r.x) * 0.5f, rh = (r.w - r.y) * 0.5f;
        float tx = (gx - rx) / (rw + 1e-8f);
        float ty = (gy - ry) / (rh + 1e-8f);
        float tw = logf(gw / (rw + 1e-8f));
        float th = logf(gh / (rh + 1e-8f));

        float d0 = reg0 - tx, d1 = reg1 - ty, d2 = reg2 - tw, d3 = reg3 - th;
        float a0 = fabsf(d0), a1 = fabsf(d1), a2 = fabsf(d2), a3 = fabsf(d3);
        float s0 = (a0 < 1.f) ? 0.5f * a0 * a0 : a0 - 0.5f;
        float s1 = (a1 < 1.f) ? 0.5f * a1 * a1 : a1 - 0.5f;
        float s2 = (a2 < 1.f) ? 0.5f * a2 * a2 : a2 - 0.5f;
        float s3 = (a3 < 1.f) ? 0.5f * a3 * a3 : a3 - 0.5f;
        float sl1 = s0 + s1 + s2 + s3;

        px += ce_bg;
        py += ce_fg * ps * maskf;
        pz += maskf;
        pw += sl1 * maskf * ps;
    }

    // --- deterministic 64-lane shuffle reduce ---
    #pragma unroll
    for (int off = 32; off > 0; off >>= 1) {
        px += __shfl_down(px, off);
        py += __shfl_down(py, off);
        pz += __shfl_down(pz, off);
        pw += __shfl_down(pw, off);
    }
    if (lane == 0) {
        partials[(size_t)blk * 4 + 0] = px;
        partials[(size_t)blk * 4 + 1] = py;
        partials[(size_t)blk * 4 + 2] = pz;
        partials[(size_t)blk * 4 + 3] = pw;
    }
}

// ---------------------------------------------------------------------------
// Final combine: lanes 0..15 each sum their batch's 32 block-partials in
// fixed order, compute per-batch terms, wave shuffle-reduce, one write.
// ---------------------------------------------------------------------------
__global__ __launch_bounds__(64) void oicr_final(
    const float* __restrict__ partials,
    const int*   __restrict__ gt_counts,
    float* __restrict__ out)
{
    const int lane = threadIdx.x;
    float S0 = 0.f, S1 = 0.f, S2 = 0.f, S3 = 0.f;
    float c_term = 0.f, cbg_term = 0.f, bg_term = 0.f, l1_term = 0.f;
    if (lane < BSZ) {
        for (int blk = 0; blk < BPB; ++blk) {
            const float* q = partials + (size_t)(lane * BPB + blk) * 4;
            S0 += q[0]; S1 += q[1]; S2 += q[2]; S3 += q[3];
        }
        bool has = gt_counts[lane] > 0;
        float c_fg       = S1 / (S2 + 1e-7f);
        float ce_bg_mean = S0 / (float)NP;
        float l1b        = S3 / (float)(BSZ * NP);
        c_term   = has ? c_fg : 0.f;
        cbg_term = has ? 0.f : ce_bg_mean;
        bg_term  = has ? 0.f : (float)NP;
        l1_term  = has ? l1b : 0.f;
    }
    #pragma unroll
    for (int off = 32; off > 0; off >>= 1) {
        c_term   += __shfl_down(c_term, off);
        cbg_term += __shfl_down(cbg_term, off);
        bg_term  += __shfl_down(bg_term, off);
        l1_term  += __shfl_down(l1_term, off);
    }
    if (lane == 0) {
        out[0] = (c_term + cbg_term / (bg_term + 1e-7f)) / ((float)BSZ + 1e-7f)
                 + l1_term;
    }
}

extern "C" void kernel_launch(void* const* d_in, const int* in_sizes, int n_in,
                              void* d_out, int out_size, void* d_ws, size_t ws_size,
                              hipStream_t stream)
{
    const float* v         = (const float*)d_in[0];
    const float* gt_boxes  = (const float*)d_in[1];
    const int*   gt_counts = (const int*)  d_in[2];
    const float* rois      = (const float*)d_in[3];
    const float* labels    = (const float*)d_in[4];
    const float* pre_score = (const float*)d_in[5];
    const float* cls_w     = (const float*)d_in[6];
    const float* cls_b     = (const float*)d_in[7];
    const float* reg_w     = (const float*)d_in[8];
    const float* reg_b     = (const float*)d_in[9];
    float* out      = (float*)d_out;
    float* partials = (float*)d_ws;   // 512 blocks * 4 floats = 8 KB

    oicr_main<<<dim3(NBLK), dim3(256), 0, stream>>>(
        v, gt_boxes, gt_counts, rois, labels, pre_score,
        cls_w, cls_b, reg_w, reg_b, partials);
    oicr_final<<<dim3(1), dim3(64), 0, stream>>>(partials, gt_counts, out);
}

// Round 9
// 39.277 us; speedup vs baseline: 1.9479x; 1.3885x over previous
//
#include <hip/hip_runtime.h>
#include <math.h>

#define BSZ 16
#define NP 4096
#define MAXGT 32
#define CIN 512
#define NCLS 4
#define RPT 2                      // rows (proposals) per thread (stream loop)
#define PB (64 * RPT)              // proposals per block = 128
#define NBLK (BSZ * NP / PB)       // 512 blocks
#define BPB (NP / PB)              // 32 blocks per batch

typedef float f32x4 __attribute__((ext_vector_type(4)));

// ---------------------------------------------------------------------------
// Main kernel (R3 champion stream core): 4 waves/block, 128 proposals/block
// (2/thread). Wave w computes dot-product partials over K-quarter w; weights
// read via wave-uniform addresses (scalar K$ path, no LDS); v streamed with
// plain cached loads, unroll 8. Epilogue spread over 2 waves (threads 0..127,
// one row each) instead of wave 0 doing 2 rows — halves the epilogue tail.
// ---------------------------------------------------------------------------
__global__ __launch_bounds__(256, 2) void oicr_main(
    const float* __restrict__ v,
    const float* __restrict__ gt_boxes,
    const int*   __restrict__ gt_counts,
    const float* __restrict__ rois,
    const float* __restrict__ labels,
    const float* __restrict__ pre_score,
    const float* __restrict__ cls_w,
    const float* __restrict__ cls_b,
    const float* __restrict__ reg_w,
    const float* __restrict__ reg_b,
    float* __restrict__ partials)
{
    __shared__ float red8[4][PB][9];      // 18.4 KB, stride 9 -> conflict-free
    __shared__ float red2[2][4];
    __shared__ float s_bias[8];
    __shared__ float g_x0[MAXGT], g_y0[MAXGT], g_x1[MAXGT], g_y1[MAXGT];
    __shared__ float g_area[MAXGT];
    __shared__ int   g_valid[MAXGT];
    __shared__ int   s_label;

    const int tid   = threadIdx.x;
    const int lane  = tid & 63;
    const int wv    = tid >> 6;                   // wave id 0..3 (K-quarter)
    const int blk   = blockIdx.x;
    const int b     = blk >> 5;                   // 32 blocks per batch
    const int pbase = (blk & 31) * PB;
    const int row0  = b * NP + pbase + lane;      // this thread's 2 stream rows
    const int row1  = row0 + 64;

    // --- tiny per-batch metadata (consumed only after the barrier) ---
    if (tid < 8) s_bias[tid] = (tid < 4) ? cls_b[tid] : reg_b[tid - 4];
    if (tid < MAXGT) {
        int cnt = gt_counts[b];
        const float* g = gt_boxes + (size_t)(b * MAXGT + tid) * 4;
        float x0 = g[0], y0 = g[1], x1 = g[2], y1 = g[3];
        g_x0[tid] = x0; g_y0[tid] = y0; g_x1[tid] = x1; g_y1[tid] = y1;
        g_area[tid] = (x1 - x0) * (y1 - y0);
        g_valid[tid] = (tid < cnt) ? 1 : 0;
    }
    if (tid == 0) {
        const float* L = labels + b * NCLS;
        int bi = 0; float bv = L[0];
        #pragma unroll
        for (int c = 1; c < NCLS; ++c) { if (L[c] > bv) { bv = L[c]; bi = c; } }
        s_label = bi;
    }

    // --- dot-product partials over this wave's K-quarter, 2 rows/thread ---
    const int kq = __builtin_amdgcn_readfirstlane(wv);   // wave-uniform
    float acc0[8], acc1[8];
    #pragma unroll
    for (int c = 0; c < 8; ++c) { acc0[c] = 0.f; acc1[c] = 0.f; }

    const f32x4* vr0 = (const f32x4*)(v + (size_t)row0 * CIN) + kq * 32;
    const f32x4* vr1 = (const f32x4*)(v + (size_t)row1 * CIN) + kq * 32;

    #pragma unroll 8
    for (int i = 0; i < 32; ++i) {
        f32x4 a0 = vr0[i];
        f32x4 a1 = vr1[i];
        const int k = (kq * 32 + i) * 4;             // uniform
        #pragma unroll
        for (int c = 0; c < 4; ++c) {
            const f32x4 wc = *(const f32x4*)&cls_w[c * CIN + k];  // uniform -> s_load
            const f32x4 wr = *(const f32x4*)&reg_w[c * CIN + k];  // uniform -> s_load
            acc0[c]     += a0[0]*wc[0] + a0[1]*wc[1] + a0[2]*wc[2] + a0[3]*wc[3];
            acc1[c]     += a1[0]*wc[0] + a1[1]*wc[1] + a1[2]*wc[2] + a1[3]*wc[3];
            acc0[4 + c] += a0[0]*wr[0] + a0[1]*wr[1] + a0[2]*wr[2] + a0[3]*wr[3];
            acc1[4 + c] += a1[0]*wr[0] + a1[1]*wr[1] + a1[2]*wr[2] + a1[3]*wr[3];
        }
    }

    #pragma unroll
    for (int c = 0; c < 8; ++c) {
        red8[wv][lane][c]      = acc0[c];   // row pbase + lane
        red8[wv][64 + lane][c] = acc1[c];   // row pbase + 64 + lane
    }
    __syncthreads();

    // --- epilogue on 2 waves: thread t < 128 handles block-row t ---
    if (tid < 128) {
        const int li  = tid;
        const int row = b * NP + pbase + li;

        float acc[8];
        #pragma unroll
        for (int c = 0; c < 8; ++c)
            acc[c] = red8[0][li][c] + red8[1][li][c] +
                     red8[2][li][c] + red8[3][li][c];

        const float cls0 = acc[0] + s_bias[0];
        const float cls1 = acc[1] + s_bias[1];
        const float cls2 = acc[2] + s_bias[2];
        const float cls3 = acc[3] + s_bias[3];
        const float reg0 = acc[4] + s_bias[4];
        const float reg1 = acc[5] + s_bias[5];
        const float reg2 = acc[6] + s_bias[6];
        const float reg3 = acc[7] + s_bias[7];

        const int lbl = s_label;

        // background CE on raw logits
        float mB = fmaxf(fmaxf(cls0, cls1), fmaxf(cls2, cls3));
        float lseB = mB + logf(expf(cls0 - mB) + expf(cls1 - mB) +
                               expf(cls2 - mB) + expf(cls3 - mB));
        float clsL = (lbl == 0) ? cls0 : (lbl == 1) ? cls1 : (lbl == 2) ? cls2 : cls3;
        float ce_bg = lseB - clsL;

        // foreground CE on clipped logits
        const float lo = 1e-7f, hi2 = 1.f - 1e-7f;
        float cc0 = fminf(fmaxf(cls0, lo), hi2);
        float cc1 = fminf(fmaxf(cls1, lo), hi2);
        float cc2 = fminf(fmaxf(cls2, lo), hi2);
        float cc3 = fminf(fmaxf(cls3, lo), hi2);
        float mF = fmaxf(fmaxf(cc0, cc1), fmaxf(cc2, cc3));
        float lseF = mF + logf(expf(cc0 - mF) + expf(cc1 - mF) +
                               expf(cc2 - mF) + expf(cc3 - mF));
        float ccL = (lbl == 0) ? cc0 : (lbl == 1) ? cc1 : (lbl == 2) ? cc2 : cc3;
        float ce_fg = lseF - ccL;
        float ps = pre_score[(size_t)row * NCLS + lbl];

        // IoU over 32 GTs: mask + first-occurrence argmax
        float4 r = *(const float4*)(rois + (size_t)row * 4);
        float rarea = (r.z - r.x) * (r.w - r.y);
        float best = -3.0e38f;
        int   bi = 0;
        int   mk = 0;
        #pragma unroll
        for (int g = 0; g < MAXGT; ++g) {
            float ix0 = fmaxf(r.x, g_x0[g]);
            float iy0 = fmaxf(r.y, g_y0[g]);
            float ix1 = fminf(r.z, g_x1[g]);
            float iy1 = fminf(r.w, g_y1[g]);
            float iw = fmaxf(ix1 - ix0, 0.f);
            float ih = fmaxf(iy1 - iy0, 0.f);
            float inter = iw * ih;
            float iou = inter / (g_area[g] + rarea - inter);
            iou = g_valid[g] ? iou : -1.0f;
            if (iou > best) { best = iou; bi = g; }   // strict > => first max
            mk |= (iou > 0.5f) ? 1 : 0;
        }
        float maskf = mk ? 1.f : 0.f;

        // bbox targets + smooth L1
        float gx0 = g_x0[bi], gy0 = g_y0[bi], gx1 = g_x1[bi], gy1 = g_y1[bi];
        float gx = (gx1 + gx0) * 0.5f, gy = (gy1 + gy0) * 0.5f;
        float gw = (gx1 - gx0) * 0.5f, gh = (gy1 - gy0) * 0.5f;
        float rx = (r.z + r.x) * 0.5f, ry = (r.w + r.y) * 0.5f;
        float rw = (r.z - r.x) * 0.5f, rh = (r.w - r.y) * 0.5f;
        float tx = (gx - rx) / (rw + 1e-8f);
        float ty = (gy - ry) / (rh + 1e-8f);
        float tw = logf(gw / (rw + 1e-8f));
        float th = logf(gh / (rh + 1e-8f));

        float d0 = reg0 - tx, d1 = reg1 - ty, d2 = reg2 - tw, d3 = reg3 - th;
        float a0 = fabsf(d0), a1 = fabsf(d1), a2 = fabsf(d2), a3 = fabsf(d3);
        float s0 = (a0 < 1.f) ? 0.5f * a0 * a0 : a0 - 0.5f;
        float s1 = (a1 < 1.f) ? 0.5f * a1 * a1 : a1 - 0.5f;
        float s2 = (a2 < 1.f) ? 0.5f * a2 * a2 : a2 - 0.5f;
        float s3 = (a3 < 1.f) ? 0.5f * a3 * a3 : a3 - 0.5f;
        float sl1 = s0 + s1 + s2 + s3;

        float px = ce_bg;
        float py = ce_fg * ps * maskf;
        float pz = maskf;
        float pw = sl1 * maskf * ps;

        // deterministic 64-lane shuffle reduce within each of the 2 waves
        #pragma unroll
        for (int off = 32; off > 0; off >>= 1) {
            px += __shfl_down(px, off);
            py += __shfl_down(py, off);
            pz += __shfl_down(pz, off);
            pw += __shfl_down(pw, off);
        }
        if (lane == 0) {
            red2[wv][0] = px; red2[wv][1] = py;
            red2[wv][2] = pz; red2[wv][3] = pw;
        }
    }
    __syncthreads();
    if (tid == 0) {
        partials[(size_t)blk * 4 + 0] = red2[0][0] + red2[1][0];
        partials[(size_t)blk * 4 + 1] = red2[0][1] + red2[1][1];
        partials[(size_t)blk * 4 + 2] = red2[0][2] + red2[1][2];
        partials[(size_t)blk * 4 + 3] = red2[0][3] + red2[1][3];
    }
}

// ---------------------------------------------------------------------------
// Final combine, parallelized: 256 threads. Threads t with bat=t>>4, sub=t&15
// sum 2 of batch bat's 32 block-partials each; width-16 shuffle tree reduces
// to sub==0; per-batch terms go to LDS; thread 0 does the fixed-order
// 16-batch combine and writes out[0]. Serial dependent-load chain: 8 loads.
// ---------------------------------------------------------------------------
__global__ __launch_bounds__(256) void oicr_final(
    const float* __restrict__ partials,
    const int*   __restrict__ gt_counts,
    float* __restrict__ out)
{
    __shared__ float sb[BSZ][4];
    const int t   = threadIdx.x;
    const int bat = t >> 4;           // 0..15
    const int sub = t & 15;           // 0..15

    float S0 = 0.f, S1 = 0.f, S2 = 0.f, S3 = 0.f;
    #pragma unroll
    for (int j = 0; j < 2; ++j) {
        const float* q = partials + ((size_t)bat * BPB + sub * 2 + j) * 4;
        S0 += q[0]; S1 += q[1]; S2 += q[2]; S3 += q[3];
    }
    #pragma unroll
    for (int off = 8; off > 0; off >>= 1) {
        S0 += __shfl_down(S0, off, 16);
        S1 += __shfl_down(S1, off, 16);
        S2 += __shfl_down(S2, off, 16);
        S3 += __shfl_down(S3, off, 16);
    }
    if (sub == 0) {
        bool has = gt_counts[bat] > 0;
        float c_fg       = S1 / (S2 + 1e-7f);
        float ce_bg_mean = S0 / (float)NP;
        float l1b        = S3 / (float)(BSZ * NP);
        sb[bat][0] = has ? c_fg : 0.f;
        sb[bat][1] = has ? 0.f : ce_bg_mean;
        sb[bat][2] = has ? 0.f : (float)NP;
        sb[bat][3] = has ? l1b : 0.f;
    }
    __syncthreads();
    if (t == 0) {
        float c = 0.f, cb = 0.f, bg = 0.f, l1 = 0.f;
        #pragma unroll
        for (int i = 0; i < BSZ; ++i) {
            c  += sb[i][0];
            cb += sb[i][1];
            bg += sb[i][2];
            l1 += sb[i][3];
        }
        out[0] = (c + cb / (bg + 1e-7f)) / ((float)BSZ + 1e-7f) + l1;
    }
}

extern "C" void kernel_launch(void* const* d_in, const int* in_sizes, int n_in,
                              void* d_out, int out_size, void* d_ws, size_t ws_size,
                              hipStream_t stream)
{
    const float* v         = (const float*)d_in[0];
    const float* gt_boxes  = (const float*)d_in[1];
    const int*   gt_counts = (const int*)  d_in[2];
    const float* rois      = (const float*)d_in[3];
    const float* labels    = (const float*)d_in[4];
    const float* pre_score = (const float*)d_in[5];
    const float* cls_w     = (const float*)d_in[6];
    const float* cls_b     = (const float*)d_in[7];
    const float* reg_w     = (const float*)d_in[8];
    const float* reg_b     = (const float*)d_in[9];
    float* out      = (float*)d_out;
    float* partials = (float*)d_ws;   // 512 blocks * 4 floats = 8 KB

    oicr_main<<<dim3(NBLK), dim3(256), 0, stream>>>(
        v, gt_boxes, gt_counts, rois, labels, pre_score,
        cls_w, cls_b, reg_w, reg_b, partials);
    oicr_final<<<dim3(1), dim3(256), 0, stream>>>(partials, gt_counts, out);
}